// Round 1
// baseline (28.266 us; speedup 1.0000x reference)
//
#include <hip/hip_runtime.h>

// Adaptive avg pool 2D: (B=16, C=768, H=64, W=48) f32 -> (B, C, 7, 7) f32.
// One block per (b,c) plane. Coalesced float4 load of the 12KB plane to LDS,
// then separable two-stage pooling (W then H) entirely in LDS.

#define H_IN 64
#define W_IN 48
#define HO 7
#define WO 7
#define PLANE (H_IN * W_IN)   // 3072 floats

__global__ __launch_bounds__(256) void
adaptive_pool_kernel(const float* __restrict__ x, float* __restrict__ out) {
    __shared__ float xs[PLANE];        // 12 KB: the input plane
    __shared__ float ts[H_IN * WO];    // 1.75 KB: row-pooled [64][7]

    const int plane = blockIdx.x;
    const int tid   = threadIdx.x;
    const float* xp = x + (size_t)plane * PLANE;

    // ---- Stage 0: coalesced float4 load into LDS (768 float4 / 256 thr = 3 each)
    const float4* xp4 = reinterpret_cast<const float4*>(xp);
    float4* xs4 = reinterpret_cast<float4*>(xs);
    #pragma unroll
    for (int i = 0; i < 3; ++i) {
        const int idx = tid + i * 256;
        xs4[idx] = xp4[idx];
    }
    __syncthreads();

    // ---- Stage 1: pool along W: ts[row][ow] = mean(xs[row][ws..we))
    // 64*7 = 448 items over 256 threads -> 2 iterations
    #pragma unroll
    for (int i = 0; i < 2; ++i) {
        const int item = tid + i * 256;
        if (item < H_IN * WO) {
            const int row = item / WO;
            const int ow  = item % WO;
            const int ws  = (ow * W_IN) / WO;
            const int we  = ((ow + 1) * W_IN + WO - 1) / WO;
            float s = 0.0f;
            #pragma unroll
            for (int w = 0; w < 8; ++w) {          // max window = 8
                if (ws + w < we) s += xs[row * W_IN + ws + w];
            }
            ts[item] = s * (1.0f / (float)(we - ws));
        }
    }
    __syncthreads();

    // ---- Stage 2: pool along H: out[oh][ow] = mean(ts[hs..he)[ow])
    if (tid < HO * WO) {
        const int oh = tid / WO;
        const int ow = tid % WO;
        const int hs = (oh * H_IN) / HO;
        const int he = ((oh + 1) * H_IN + HO - 1) / HO;   // always hs+10 here
        float s = 0.0f;
        #pragma unroll
        for (int h = 0; h < 10; ++h) {             // window = 10 for 64->7
            if (hs + h < he) s += ts[(hs + h) * WO + ow];
        }
        out[(size_t)plane * (HO * WO) + tid] = s * (1.0f / (float)(he - hs));
    }
}

extern "C" void kernel_launch(void* const* d_in, const int* in_sizes, int n_in,
                              void* d_out, int out_size, void* d_ws, size_t ws_size,
                              hipStream_t stream) {
    const float* x = (const float*)d_in[0];
    float* out = (float*)d_out;
    const int nplanes = in_sizes[0] / PLANE;   // 16*768 = 12288
    adaptive_pool_kernel<<<nplanes, 256, 0, stream>>>(x, out);
}